// Round 1
// baseline (419.672 us; speedup 1.0000x reference)
//
#include <hip/hip_runtime.h>

// Decoder scan: B=256 batch, T=128 enc steps, M=64, P=64, 127 sequential steps.
// One block per batch element (256 blocks = 256 CUs), 512 threads (8 waves).
// enc[b], Ue[b] (padded), Wd staged in LDS; ctx carried as 8 per-wave partials.

#define Bn 256
#define Tn 128
#define Mn 64
#define Pn 64
#define NTH 512
#define NW 8

__device__ __forceinline__ float fexp(float x) {
    return __builtin_amdgcn_exp2f(x * 1.44269504088896341f);
}
__device__ __forceinline__ float frcp(float x) {
    return __builtin_amdgcn_rcpf(x);
}
__device__ __forceinline__ float fsig(float x) {
    return frcp(1.0f + fexp(-x));
}
__device__ __forceinline__ float ftanh(float x) {
    return 1.0f - 2.0f * frcp(1.0f + fexp(2.0f * x));
}

// LDS layout (floats):
//  enc_s  [128][64]      8192
//  Ue_s   [128][65]      8320   (pad 65: e-phase reads t*65+m -> conflict-free)
//  Wd_s   [128][64]      8192
//  Ud_s   [64][64]       4096   (init only)
//  pre_s  [256]           256   (h0@Uk+bk)
//  dpart  [8][64]         512
//  dproj  [64]             64
//  e_s    [128]           128
//  ctxp   [8][64]         512
//  x_s    [127]           127
#define OFF_ENC   0
#define OFF_UE    8192
#define OFF_WD    (8192 + 8320)
#define OFF_UD    (OFF_WD + 8192)
#define OFF_PRE   (OFF_UD + 4096)
#define OFF_DPART (OFF_PRE + 256)
#define OFF_DPROJ (OFF_DPART + 512)
#define OFF_ES    (OFF_DPROJ + 64)
#define OFF_CTXP  (OFF_ES + 128)
#define OFF_XS    (OFF_CTXP + 512)
#define SMEM_FLOATS (OFF_XS + 127 + 1)

__global__ __launch_bounds__(NTH, 1)
void decoder_kernel(const float* __restrict__ data, const float* __restrict__ enc,
                    const float* __restrict__ h0, const float* __restrict__ s0,
                    const float* __restrict__ W_dense, const float* __restrict__ b_dense,
                    const float* __restrict__ Wk, const float* __restrict__ Uk,
                    const float* __restrict__ bk,
                    const float* __restrict__ Wd, const float* __restrict__ bWd,
                    const float* __restrict__ Ud, const float* __restrict__ bUd,
                    const float* __restrict__ vd, const float* __restrict__ bvd,
                    const float* __restrict__ Wvb, const float* __restrict__ bvb,
                    const float* __restrict__ Wb, const float* __restrict__ bWb,
                    float* __restrict__ out)
{
    extern __shared__ float smem[];
    float* enc_s   = smem + OFF_ENC;
    float* Ue_s    = smem + OFF_UE;
    float* Wd_s    = smem + OFF_WD;
    float* Ud_s    = smem + OFF_UD;
    float* pre_s   = smem + OFF_PRE;
    float* dpart   = smem + OFF_DPART;
    float* dproj_s = smem + OFF_DPROJ;
    float* e_s     = smem + OFF_ES;
    float* ctxp    = smem + OFF_CTXP;
    float* x_s     = smem + OFF_XS;

    const int b    = blockIdx.x;
    const int tid  = threadIdx.x;
    const int lane = tid & 63;
    const int wv   = tid >> 6;

    // ---- init: stage enc[b], Wd, Ud; x row; pre = h0@Uk + bk; zero ctxp ----
    {
        const float4* encg = (const float4*)(enc + (size_t)b * Tn * Mn);
        float4* enc4 = (float4*)enc_s;
        #pragma unroll
        for (int i = 0; i < 4; i++) enc4[tid + i * NTH] = encg[tid + i * NTH];

        const float4* wdg = (const float4*)Wd;
        float4* wd4 = (float4*)Wd_s;
        #pragma unroll
        for (int i = 0; i < 4; i++) wd4[tid + i * NTH] = wdg[tid + i * NTH];

        const float4* udg = (const float4*)Ud;
        float4* ud4 = (float4*)Ud_s;
        ud4[tid] = udg[tid];
        ud4[tid + NTH] = udg[tid + NTH];

        if (tid < Tn - 1) x_s[tid] = data[(size_t)b * (Tn - 1) + tid];

        if (tid < 4 * Pn) {
            float s = bk[tid];
            const float* h0b = h0 + b * Pn;
            #pragma unroll
            for (int k = 0; k < Pn; k++) s = fmaf(h0b[k], Uk[k * 4 * Pn + tid], s);
            pre_s[tid] = s;
        }
        ctxp[tid] = 0.0f;  // exactly 512 floats
    }
    __syncthreads();

    // ---- Ue = enc @ Ud + bUd  (each thread: one t, 16 m's) ----
    {
        const int t = tid >> 2, q = tid & 3, m0 = q * 16;
        float acc[16];
        #pragma unroll
        for (int j = 0; j < 16; j++) acc[j] = bUd[m0 + j];
        for (int k = 0; k < Mn; k++) {
            float a = enc_s[t * Mn + k];
            const float4* ud = (const float4*)&Ud_s[k * Mn + m0];
            #pragma unroll
            for (int j4 = 0; j4 < 4; j4++) {
                float4 u = ud[j4];
                acc[4 * j4 + 0] = fmaf(a, u.x, acc[4 * j4 + 0]);
                acc[4 * j4 + 1] = fmaf(a, u.y, acc[4 * j4 + 1]);
                acc[4 * j4 + 2] = fmaf(a, u.z, acc[4 * j4 + 2]);
                acc[4 * j4 + 3] = fmaf(a, u.w, acc[4 * j4 + 3]);
            }
        }
        #pragma unroll
        for (int j = 0; j < 16; j++) Ue_s[t * (Mn + 1) + m0 + j] = acc[j];
    }

    // ---- per-lane loop-invariant registers ----
    const float W0  = W_dense[0];
    const float bd  = b_dense[0];
    const float Wde = W_dense[1 + lane];
    const float wk_i = Wk[lane], wk_f = Wk[64 + lane],
                wk_g = Wk[128 + lane], wk_o = Wk[192 + lane];
    const float s0v   = s0[b * Pn + lane];
    const float bWd_l = bWd[lane];
    const float bvd0  = bvd[0];
    const int   et = tid >> 2, eq = tid & 3, em0 = eq * 16;
    float vdr2[16];
    float sumvd = 0.0f;
    #pragma unroll
    for (int j = 0; j < 16; j++) {
        float v = vd[em0 + j];
        vdr2[j] = -2.0f * v;
        sumvd += v;
    }
    const float pre_i_g = pre_s[lane];        // pre_s written before first sync
    const float pre_f_g = pre_s[64 + lane];
    const float pre_g_g = pre_s[128 + lane];
    const float pre_o_g = pre_s[192 + lane];
    __syncthreads();  // Ue_s ready

    float h = 0.0f, c = 0.0f;

    for (int st = 0; st < Tn - 1; ++st) {
        // phase a: y = x*W0 + sum_m ctx[m]*W_dense[1+m] + bd   (wave-redundant)
        float ya = 0.0f;
        #pragma unroll
        for (int w = 0; w < NW; w++) ya += ctxp[w * 64 + lane];
        ya *= Wde;
        #pragma unroll
        for (int k = 32; k >= 1; k >>= 1) ya += __shfl_xor(ya, k);
        float y = fmaf(x_s[st], W0, ya + bd);

        // phase b: LSTM gates (state resets to h0,s0 each step; pre = h0@Uk+bk)
        float zi = fmaf(y, wk_i, pre_i_g);
        float zf = fmaf(y, wk_f, pre_f_g);
        float zg = fmaf(y, wk_g, pre_g_g);
        float zo = fmaf(y, wk_o, pre_o_g);
        c = fsig(zf) * s0v + fsig(zi) * ftanh(zg);
        h = fsig(zo) * ftanh(c);

        // phase c: dproj partials — wave wv covers k in [16wv, 16wv+16)
        {
            float hv = (wv < 4) ? h : c;
            int base = (wv & 3) * 16;
            int k0 = wv * 16;
            float part = 0.0f;
            #pragma unroll
            for (int j = 0; j < 16; j++) {
                float a = __shfl(hv, base + j);
                part = fmaf(a, Wd_s[(k0 + j) * Mn + lane], part);
            }
            dpart[wv * 64 + lane] = part;
        }
        __syncthreads();  // B1

        // phase d: dproj[m] = sum_w dpart[w][m] + bWd[m]
        if (wv == 0) {
            float s = bWd_l;
            #pragma unroll
            for (int w = 0; w < NW; w++) s += dpart[w * 64 + lane];
            dproj_s[lane] = s;
        }
        __syncthreads();  // B2

        // phase e: e[t] = sum_m tanh(dproj[m]+Ue[t][m])*vd[m] + bvd
        //          thread: one t (=tid>>2), 16 m's; tanh = 1-2r folded into vd
        {
            float dv[16];
            #pragma unroll
            for (int j = 0; j < 16; j++) dv[j] = dproj_s[em0 + j];
            float acc = 0.0f;
            #pragma unroll
            for (int j = 0; j < 16; j++) {
                float x = dv[j] + Ue_s[et * (Mn + 1) + em0 + j];
                float r = frcp(1.0f + fexp(2.0f * x));
                acc = fmaf(vdr2[j], r, acc);
            }
            acc += sumvd;
            acc += __shfl_xor(acc, 1);
            acc += __shfl_xor(acc, 2);
            if (eq == 0) e_s[et] = acc + bvd0;
        }
        __syncthreads();  // B3

        // phase f+g: softmax stats (wave-redundant butterfly) + ctx partials
        {
            float a  = e_s[lane];
            float b2 = e_s[64 + lane];
            float mx = fmaxf(a, b2);
            #pragma unroll
            for (int k = 32; k >= 1; k >>= 1) mx = fmaxf(mx, __shfl_xor(mx, k));
            float se = fexp(a - mx) + fexp(b2 - mx);
            #pragma unroll
            for (int k = 32; k >= 1; k >>= 1) se += __shfl_xor(se, k);
            float invS = frcp(se);

            float part = 0.0f;
            int t0 = wv * 16;
            #pragma unroll
            for (int j = 0; j < 16; j++) {
                int t = t0 + j;
                float bt = fexp(e_s[t] - mx);
                part = fmaf(bt, enc_s[t * Mn + lane], part);
            }
            ctxp[wv * 64 + lane] = part * invS;
        }
        __syncthreads();  // B4
    }

    // ---- epilogue: out[b][p] = ((hc @ Wvb + bvb) * Wb[p]) + bWb[p] ----
    if (wv == 0) {
        float ctxm = 0.0f;
        #pragma unroll
        for (int w = 0; w < NW; w++) ctxm += ctxp[w * 64 + lane];
        float part = h * Wvb[lane] + ctxm * Wvb[64 + lane];
        #pragma unroll
        for (int k = 32; k >= 1; k >>= 1) part += __shfl_xor(part, k);
        float v = part + bvb[0];
        out[(size_t)b * Pn + lane] = fmaf(v, Wb[lane], bWb[lane]);
    }
}

extern "C" void kernel_launch(void* const* d_in, const int* in_sizes, int n_in,
                              void* d_out, int out_size, void* d_ws, size_t ws_size,
                              hipStream_t stream) {
    const float* data    = (const float*)d_in[0];
    const float* enc     = (const float*)d_in[1];
    const float* h0      = (const float*)d_in[2];
    const float* s0      = (const float*)d_in[3];
    const float* W_dense = (const float*)d_in[4];
    const float* b_dense = (const float*)d_in[5];
    const float* Wk      = (const float*)d_in[6];
    const float* Uk      = (const float*)d_in[7];
    const float* bk      = (const float*)d_in[8];
    const float* Wd      = (const float*)d_in[9];
    const float* bWd     = (const float*)d_in[10];
    const float* Ud      = (const float*)d_in[11];
    const float* bUd     = (const float*)d_in[12];
    const float* vd      = (const float*)d_in[13];
    const float* bvd     = (const float*)d_in[14];
    const float* Wvb     = (const float*)d_in[15];
    const float* bvb     = (const float*)d_in[16];
    const float* Wb      = (const float*)d_in[17];
    const float* bWb     = (const float*)d_in[18];

    decoder_kernel<<<Bn, NTH, SMEM_FLOATS * sizeof(float), stream>>>(
        data, enc, h0, s0, W_dense, b_dense, Wk, Uk, bk,
        Wd, bWd, Ud, bUd, vd, bvd, Wvb, bvb, Wb, bWb, (float*)d_out);
}

// Round 2
// 316.077 us; speedup vs baseline: 1.3278x; 1.3278x over previous
//
#include <hip/hip_runtime.h>

// Decoder scan: B=256 batch, T=128, M=64, P=64, 127 sequential steps.
// One block per batch element (256 blocks = 256 CUs), 512 threads (8 waves).
// Cross-lane work via DPP adds + v_readlane (VALU pipe) instead of ds_bpermute.
// Wd and enc held in per-lane registers; Ue in LDS with stride-68 padding.

#define Bn 256
#define Tn 128
#define Mn 64
#define Pn 64
#define NTH 512
#define NW 8
#define UST 68   // padded stride (floats) for enc_s / Ue_s / Ud_s
#define DPST 72  // padded stride for dpart
#define K2C 2.885390081777927f  // 2 * log2(e)

__device__ __forceinline__ float fexp(float x) {   // e^x
    return __builtin_amdgcn_exp2f(x * 1.44269504088896341f);
}
__device__ __forceinline__ float fexp2(float x) { return __builtin_amdgcn_exp2f(x); }
__device__ __forceinline__ float frcp(float x) { return __builtin_amdgcn_rcpf(x); }
__device__ __forceinline__ float fsig(float x) { return frcp(1.0f + fexp(-x)); }
__device__ __forceinline__ float ftanh(float x) { return 1.0f - 2.0f * frcp(1.0f + fexp(2.0f * x)); }

template <int CTRL>
__device__ __forceinline__ float dppmov(float x) {
    // invalid source lanes contribute old=0 (safe for additive reductions)
    return __int_as_float(__builtin_amdgcn_update_dpp(
        0, __float_as_int(x), CTRL, 0xf, 0xf, false));
}
__device__ __forceinline__ float rdlane(float x, int l) {
    return __int_as_float(__builtin_amdgcn_readlane(__float_as_int(x), l));
}
// full 64-lane sum; total lands in lane 63, returned uniform
__device__ __forceinline__ float wavesum(float x) {
    x += dppmov<0x111>(x);  // row_shr:1
    x += dppmov<0x112>(x);  // row_shr:2
    x += dppmov<0x114>(x);  // row_shr:4
    x += dppmov<0x118>(x);  // row_shr:8
    x += dppmov<0x142>(x);  // row_bcast:15
    x += dppmov<0x143>(x);  // row_bcast:31
    return rdlane(x, 63);
}

// LDS layout (floats):
#define OFF_ENC   0                       // 128*68 = 8704 (init only)
#define OFF_UE    8704                    // 128*68 = 8704
#define OFF_UD    17408                   // 64*68  = 4352 (init only)
#define OFF_PRE   21760                   // 256
#define OFF_DPART 22016                   // 8*72 = 576
#define OFF_DPROJ 22592                   // 64
#define OFF_ES    22656                   // 128
#define OFF_CTXP  22784                   // 512
#define OFF_YS    23296                   // 8
#define OFF_XS    23304                   // 128
#define SMEM_FLOATS 23432                 // 93.7 KB

__global__ __launch_bounds__(NTH, 1)
void decoder_kernel(const float* __restrict__ data, const float* __restrict__ enc,
                    const float* __restrict__ h0, const float* __restrict__ s0,
                    const float* __restrict__ W_dense, const float* __restrict__ b_dense,
                    const float* __restrict__ Wk, const float* __restrict__ Uk,
                    const float* __restrict__ bk,
                    const float* __restrict__ Wd, const float* __restrict__ bWd,
                    const float* __restrict__ Ud, const float* __restrict__ bUd,
                    const float* __restrict__ vd, const float* __restrict__ bvd,
                    const float* __restrict__ Wvb, const float* __restrict__ bvb,
                    const float* __restrict__ Wb, const float* __restrict__ bWb,
                    float* __restrict__ out)
{
    extern __shared__ float smem[];
    float* enc_s   = smem + OFF_ENC;
    float* Ue_s    = smem + OFF_UE;
    float* Ud_s    = smem + OFF_UD;
    float* pre_s   = smem + OFF_PRE;
    float* dpart   = smem + OFF_DPART;
    float* dproj_s = smem + OFF_DPROJ;
    float* e_s     = smem + OFF_ES;
    float* ctxp    = smem + OFF_CTXP;
    float* ys_s    = smem + OFF_YS;
    float* x_s     = smem + OFF_XS;

    const int b    = blockIdx.x;
    const int tid  = threadIdx.x;
    const int lane = tid & 63;
    const int wv   = tid >> 6;

    // ---- init: stage enc (stride 68), Ud (stride 68); x row; pre = h0@Uk+bk ----
    {
        const float* encg = enc + (size_t)b * Tn * Mn;
        #pragma unroll
        for (int i = 0; i < 4; i++) {
            int flat = (i * NTH + tid) * 4;          // 0..8188
            int t = flat >> 6, m = flat & 63;
            *(float4*)(enc_s + t * UST + m) = *(const float4*)(encg + flat);
        }
        #pragma unroll
        for (int i = 0; i < 2; i++) {
            int flat = (i * NTH + tid) * 4;          // 0..4092
            int k = flat >> 6, n = flat & 63;
            *(float4*)(Ud_s + k * UST + n) = *(const float4*)(Ud + flat);
        }
        if (tid < Tn - 1) x_s[tid] = data[(size_t)b * (Tn - 1) + tid];
        if (tid < 4 * Pn) {
            float s = bk[tid];
            const float* h0b = h0 + b * Pn;
            #pragma unroll
            for (int k = 0; k < Pn; k++) s = fmaf(h0b[k], Uk[k * 4 * Pn + tid], s);
            pre_s[tid] = s;
        }
        if (tid < NW) ys_s[tid] = 0.0f;
        ctxp[tid] = 0.0f;                            // 512 floats
    }
    __syncthreads();

    // ---- Ue = K2 * (enc @ Ud + bUd); thread: t = tid>>2, 16 m's ----
    const int t_e = tid >> 2, q_e = tid & 3, m0 = q_e * 16;
    {
        float acc[16];
        #pragma unroll
        for (int j = 0; j < 16; j++) acc[j] = bUd[m0 + j];
        for (int k = 0; k < Mn; k++) {
            float a = enc_s[t_e * UST + k];
            const float4* ud = (const float4*)(Ud_s + k * UST + m0);
            #pragma unroll
            for (int j4 = 0; j4 < 4; j4++) {
                float4 u = ud[j4];
                acc[4 * j4 + 0] = fmaf(a, u.x, acc[4 * j4 + 0]);
                acc[4 * j4 + 1] = fmaf(a, u.y, acc[4 * j4 + 1]);
                acc[4 * j4 + 2] = fmaf(a, u.z, acc[4 * j4 + 2]);
                acc[4 * j4 + 3] = fmaf(a, u.w, acc[4 * j4 + 3]);
            }
        }
        #pragma unroll
        for (int j4 = 0; j4 < 4; j4++) {
            float4 w;
            w.x = K2C * acc[4 * j4 + 0];
            w.y = K2C * acc[4 * j4 + 1];
            w.z = K2C * acc[4 * j4 + 2];
            w.w = K2C * acc[4 * j4 + 3];
            *(float4*)(Ue_s + t_e * UST + m0 + 4 * j4) = w;
        }
    }

    // ---- per-lane loop-invariant registers ----
    float enc_r[16], wd_r[16];
    #pragma unroll
    for (int j = 0; j < 16; j++) {
        enc_r[j] = enc_s[(16 * wv + j) * UST + lane];  // wave's 16 enc rows
        wd_r[j]  = Wd[(16 * wv + j) * Mn + lane];      // wave's 16 Wd rows
    }
    const float W0  = W_dense[0];
    const float bd  = b_dense[0];
    const float Wde = W_dense[1 + lane];
    const float wk_i = Wk[lane], wk_f = Wk[64 + lane],
                wk_g = Wk[128 + lane], wk_o = Wk[192 + lane];
    const float s0v   = s0[b * Pn + lane];
    const float bvd0  = bvd[0];
    const float bwd_r = bWd[8 * wv + (lane >> 3)];     // for phase-d writer
    float vdr2[16];
    float sumvd16 = 0.0f;
    #pragma unroll
    for (int j = 0; j < 16; j++) {
        float v = vd[m0 + j];
        vdr2[j] = -2.0f * v;
        sumvd16 += v;
    }
    const float pre_i = pre_s[lane];
    const float pre_f = pre_s[64 + lane];
    const float pre_g = pre_s[128 + lane];
    const float pre_o = pre_s[192 + lane];
    const bool hv_sel = (wv < 4);
    const int  base16 = (wv & 3) * 16;
    __syncthreads();  // Ue_s ready

    float h = 0.0f, c = 0.0f;

    for (int st = 0; st < Tn - 1; ++st) {
        // phase a: y = x*W0 + sum_w ys[w] + bd   (ys = invS-scaled ctx.Wde dots)
        float yv = ys_s[lane & 7];
        yv += dppmov<0x111>(yv);
        yv += dppmov<0x112>(yv);
        yv += dppmov<0x114>(yv);
        float y = fmaf(x_s[st], W0, rdlane(yv, 7) + bd);

        // phase b: LSTM gates (state resets to h0,s0; pre = h0@Uk+bk)
        float zi = fmaf(y, wk_i, pre_i);
        float zf = fmaf(y, wk_f, pre_f);
        float zg = fmaf(y, wk_g, pre_g);
        float zo = fmaf(y, wk_o, pre_o);
        c = fsig(zf) * s0v + fsig(zi) * ftanh(zg);
        h = fsig(zo) * ftanh(c);

        // phase c: dpart[wv][m] = sum_{j<16} hc[16wv+j] * Wd[16wv+j][m]
        {
            float hv = hv_sel ? h : c;
            float part = 0.0f;
            #pragma unroll
            for (int j = 0; j < 16; j++)
                part = fmaf(rdlane(hv, base16 + j), wd_r[j], part);
            dpart[wv * DPST + lane] = part;
        }
        __syncthreads();  // B1

        // phase d: wave wv reduces dproj slice m in [8wv, 8wv+8), pre-scaled K2
        {
            int w  = lane & 7;
            int mi = lane >> 3;
            float v = dpart[w * DPST + 8 * wv + mi];
            v += dppmov<0x111>(v);
            v += dppmov<0x112>(v);
            v += dppmov<0x114>(v);
            if ((lane & 7) == 7) dproj_s[8 * wv + mi] = K2C * (v + bwd_r);
        }
        __syncthreads();  // B2

        // phase e: e[t] = sum_m vd*tanh(dproj+Ue); store exp(e) (|e|<~3, safe)
        {
            float dv[16];
            const float4* dp4 = (const float4*)(dproj_s + m0);
            #pragma unroll
            for (int j4 = 0; j4 < 4; j4++) {
                float4 d4 = dp4[j4];
                dv[4 * j4 + 0] = d4.x; dv[4 * j4 + 1] = d4.y;
                dv[4 * j4 + 2] = d4.z; dv[4 * j4 + 3] = d4.w;
            }
            float acc = sumvd16;
            const float4* ue4 = (const float4*)(Ue_s + t_e * UST + m0);
            #pragma unroll
            for (int j4 = 0; j4 < 4; j4++) {
                float4 u = ue4[j4];
                float sA = dv[4 * j4 + 0] + u.x;
                float sB = dv[4 * j4 + 1] + u.y;
                float sC = dv[4 * j4 + 2] + u.z;
                float sD = dv[4 * j4 + 3] + u.w;
                acc = fmaf(vdr2[4 * j4 + 0], frcp(1.0f + fexp2(sA)), acc);
                acc = fmaf(vdr2[4 * j4 + 1], frcp(1.0f + fexp2(sB)), acc);
                acc = fmaf(vdr2[4 * j4 + 2], frcp(1.0f + fexp2(sC)), acc);
                acc = fmaf(vdr2[4 * j4 + 3], frcp(1.0f + fexp2(sD)), acc);
            }
            acc += dppmov<0x111>(acc);
            acc += dppmov<0x112>(acc);
            if (q_e == 3) e_s[t_e] = fexp(acc + bvd0);
        }
        __syncthreads();  // B3

        // phase f: softmax denom (DPP) + ctx partials from registers + ys
        {
            float ex0 = e_s[lane];
            float ex1 = e_s[64 + lane];
            float invS = frcp(wavesum(ex0 + ex1));
            float exv = hv_sel ? ex0 : ex1;   // wave's 16 t's live in one half
            float part = 0.0f;
            #pragma unroll
            for (int j = 0; j < 16; j++)
                part = fmaf(rdlane(exv, base16 + j), enc_r[j], part);
            float ctxv = part * invS;
            ctxp[wv * 64 + lane] = ctxv;
            float yw = ctxv * Wde;
            yw += dppmov<0x111>(yw);
            yw += dppmov<0x112>(yw);
            yw += dppmov<0x114>(yw);
            yw += dppmov<0x118>(yw);
            yw += dppmov<0x142>(yw);
            yw += dppmov<0x143>(yw);
            if (lane == 63) ys_s[wv] = yw;
        }
        __syncthreads();  // B4
    }

    // ---- epilogue: out[b][p] = ((concat(h,ctx) @ Wvb + bvb) * Wb[p]) + bWb[p] ----
    if (wv == 0) {
        float ctxm = 0.0f;
        #pragma unroll
        for (int w = 0; w < NW; w++) ctxm += ctxp[w * 64 + lane];
        float part = h * Wvb[lane] + ctxm * Wvb[64 + lane];
        float v = wavesum(part) + bvb[0];
        out[(size_t)b * Pn + lane] = fmaf(v, Wb[lane], bWb[lane]);
    }
}

extern "C" void kernel_launch(void* const* d_in, const int* in_sizes, int n_in,
                              void* d_out, int out_size, void* d_ws, size_t ws_size,
                              hipStream_t stream) {
    const float* data    = (const float*)d_in[0];
    const float* enc     = (const float*)d_in[1];
    const float* h0      = (const float*)d_in[2];
    const float* s0      = (const float*)d_in[3];
    const float* W_dense = (const float*)d_in[4];
    const float* b_dense = (const float*)d_in[5];
    const float* Wk      = (const float*)d_in[6];
    const float* Uk      = (const float*)d_in[7];
    const float* bk      = (const float*)d_in[8];
    const float* Wd      = (const float*)d_in[9];
    const float* bWd     = (const float*)d_in[10];
    const float* Ud      = (const float*)d_in[11];
    const float* bUd     = (const float*)d_in[12];
    const float* vd      = (const float*)d_in[13];
    const float* bvd     = (const float*)d_in[14];
    const float* Wvb     = (const float*)d_in[15];
    const float* bvb     = (const float*)d_in[16];
    const float* Wb      = (const float*)d_in[17];
    const float* bWb     = (const float*)d_in[18];

    decoder_kernel<<<Bn, NTH, SMEM_FLOATS * sizeof(float), stream>>>(
        data, enc, h0, s0, W_dense, b_dense, Wk, Uk, bk,
        Wd, bWd, Ud, bUd, vd, bvd, Wvb, bvb, Wb, bWb, (float*)d_out);
}

// Round 3
// 310.699 us; speedup vs baseline: 1.3507x; 1.0173x over previous
//
#include <hip/hip_runtime.h>

// Decoder scan: B=256 batch, T=128, M=64, P=64, 127 sequential steps.
// One block per batch element (256 blocks = 256 CUs), 512 threads (8 waves).
// Cross-lane via DPP adds + v_readlane (VALU pipe). Wd, enc, Ue all held in
// per-lane registers; only dpart/dproj/e_s/ctxp/ys cycle through LDS.

#define Bn 256
#define Tn 128
#define Mn 64
#define Pn 64
#define NTH 512
#define NW 8
#define UST 68   // padded stride (floats) for enc_s / Ud_s (init staging)
#define DPST 72  // padded stride for dpart
#define K2C 2.885390081777927f  // 2 * log2(e)

__device__ __forceinline__ float fexp(float x) {   // e^x
    return __builtin_amdgcn_exp2f(x * 1.44269504088896341f);
}
__device__ __forceinline__ float fexp2(float x) { return __builtin_amdgcn_exp2f(x); }
__device__ __forceinline__ float frcp(float x) { return __builtin_amdgcn_rcpf(x); }
__device__ __forceinline__ float fsig(float x) { return frcp(1.0f + fexp(-x)); }
__device__ __forceinline__ float ftanh(float x) { return 1.0f - 2.0f * frcp(1.0f + fexp(2.0f * x)); }

template <int CTRL>
__device__ __forceinline__ float dppmov(float x) {
    // invalid source lanes contribute old=0 (safe for additive reductions)
    return __int_as_float(__builtin_amdgcn_update_dpp(
        0, __float_as_int(x), CTRL, 0xf, 0xf, false));
}
__device__ __forceinline__ float rdlane(float x, int l) {
    return __int_as_float(__builtin_amdgcn_readlane(__float_as_int(x), l));
}
// full 64-lane sum; total lands in lane 63, returned uniform
__device__ __forceinline__ float wavesum(float x) {
    x += dppmov<0x111>(x);  // row_shr:1
    x += dppmov<0x112>(x);  // row_shr:2
    x += dppmov<0x114>(x);  // row_shr:4
    x += dppmov<0x118>(x);  // row_shr:8
    x += dppmov<0x142>(x);  // row_bcast:15
    x += dppmov<0x143>(x);  // row_bcast:31
    return rdlane(x, 63);
}

// LDS layout (floats):
#define OFF_ENC   0                       // 128*68 = 8704 (init only)
#define OFF_UD    8704                    // 64*68  = 4352 (init only)
#define OFF_PRE   13056                   // 256
#define OFF_DPART 13312                   // 8*72 = 576
#define OFF_DPROJ 13888                   // 64
#define OFF_ES    13952                   // 128
#define OFF_CTXP  14080                   // 512
#define OFF_YS    14592                   // 8
#define OFF_XS    14600                   // 128
#define SMEM_FLOATS 14728                 // 58.9 KB

__global__ __launch_bounds__(NTH, 1)
void decoder_kernel(const float* __restrict__ data, const float* __restrict__ enc,
                    const float* __restrict__ h0, const float* __restrict__ s0,
                    const float* __restrict__ W_dense, const float* __restrict__ b_dense,
                    const float* __restrict__ Wk, const float* __restrict__ Uk,
                    const float* __restrict__ bk,
                    const float* __restrict__ Wd, const float* __restrict__ bWd,
                    const float* __restrict__ Ud, const float* __restrict__ bUd,
                    const float* __restrict__ vd, const float* __restrict__ bvd,
                    const float* __restrict__ Wvb, const float* __restrict__ bvb,
                    const float* __restrict__ Wb, const float* __restrict__ bWb,
                    float* __restrict__ out)
{
    extern __shared__ float smem[];
    float* enc_s   = smem + OFF_ENC;
    float* Ud_s    = smem + OFF_UD;
    float* pre_s   = smem + OFF_PRE;
    float* dpart   = smem + OFF_DPART;
    float* dproj_s = smem + OFF_DPROJ;
    float* e_s     = smem + OFF_ES;
    float* ctxp    = smem + OFF_CTXP;
    float* ys_s    = smem + OFF_YS;
    float* x_s     = smem + OFF_XS;

    const int b    = blockIdx.x;
    const int tid  = threadIdx.x;
    const int lane = tid & 63;
    const int wv   = tid >> 6;

    // ---- init: stage enc (stride 68), Ud (stride 68); x row; pre = h0@Uk+bk ----
    {
        const float* encg = enc + (size_t)b * Tn * Mn;
        #pragma unroll
        for (int i = 0; i < 4; i++) {
            int flat = (i * NTH + tid) * 4;          // 0..8188
            int t = flat >> 6, m = flat & 63;
            *(float4*)(enc_s + t * UST + m) = *(const float4*)(encg + flat);
        }
        #pragma unroll
        for (int i = 0; i < 2; i++) {
            int flat = (i * NTH + tid) * 4;          // 0..4092
            int k = flat >> 6, n = flat & 63;
            *(float4*)(Ud_s + k * UST + n) = *(const float4*)(Ud + flat);
        }
        if (tid < Tn - 1) x_s[tid] = data[(size_t)b * (Tn - 1) + tid];
        if (tid < 4 * Pn) {
            float s = bk[tid];
            const float* h0b = h0 + b * Pn;
            #pragma unroll
            for (int k = 0; k < Pn; k++) s = fmaf(h0b[k], Uk[k * 4 * Pn + tid], s);
            pre_s[tid] = s;
        }
        if (tid < NW) ys_s[tid] = 0.0f;
        ctxp[tid] = 0.0f;                            // 512 floats
    }
    __syncthreads();

    // ---- Ue slice in registers: ue_r = K2 * (enc[t_e] @ Ud[:,m0+j] + bUd) ----
    const int t_e = tid >> 2, q_e = tid & 3, m0 = q_e * 16;
    float ue_r[16];
    {
        float acc[16];
        #pragma unroll
        for (int j = 0; j < 16; j++) acc[j] = bUd[m0 + j];
        for (int k = 0; k < Mn; k++) {
            float a = enc_s[t_e * UST + k];
            const float4* ud = (const float4*)(Ud_s + k * UST + m0);
            #pragma unroll
            for (int j4 = 0; j4 < 4; j4++) {
                float4 u = ud[j4];
                acc[4 * j4 + 0] = fmaf(a, u.x, acc[4 * j4 + 0]);
                acc[4 * j4 + 1] = fmaf(a, u.y, acc[4 * j4 + 1]);
                acc[4 * j4 + 2] = fmaf(a, u.z, acc[4 * j4 + 2]);
                acc[4 * j4 + 3] = fmaf(a, u.w, acc[4 * j4 + 3]);
            }
        }
        #pragma unroll
        for (int j = 0; j < 16; j++) ue_r[j] = K2C * acc[j];
    }

    // ---- per-lane loop-invariant registers ----
    float enc_r[16], wd_r[16];
    #pragma unroll
    for (int j = 0; j < 16; j++) {
        enc_r[j] = enc_s[(16 * wv + j) * UST + lane];  // wave's 16 enc rows
        wd_r[j]  = Wd[(16 * wv + j) * Mn + lane];      // wave's 16 Wd rows
    }
    const float W0  = W_dense[0];
    const float bd  = b_dense[0];
    const float Wde = W_dense[1 + lane];
    const float wk_i = Wk[lane], wk_f = Wk[64 + lane],
                wk_g = Wk[128 + lane], wk_o = Wk[192 + lane];
    const float s0v   = s0[b * Pn + lane];
    const float bvd0  = bvd[0];
    const float bwd_r = bWd[8 * wv + (lane >> 3)];     // for phase-d writer
    float vdr2[16];
    float sumvd16 = 0.0f;
    #pragma unroll
    for (int j = 0; j < 16; j++) {
        float v = vd[m0 + j];
        vdr2[j] = -2.0f * v;
        sumvd16 += v;
    }
    const float pre_i = pre_s[lane];
    const float pre_f = pre_s[64 + lane];
    const float pre_g = pre_s[128 + lane];
    const float pre_o = pre_s[192 + lane];
    const bool hv_sel = (wv < 4);
    const int  base16 = (wv & 3) * 16;

    float h = 0.0f, c = 0.0f;

    for (int st = 0; st < Tn - 1; ++st) {
        // phase a: y = x*W0 + sum_w ys[w] + bd   (ys = invS-scaled ctx.Wde dots)
        float yv = ys_s[lane & 7];
        yv += dppmov<0x111>(yv);
        yv += dppmov<0x112>(yv);
        yv += dppmov<0x114>(yv);
        float y = fmaf(x_s[st], W0, rdlane(yv, 7) + bd);

        // phase b: LSTM gates (state resets to h0,s0; pre = h0@Uk+bk)
        float zi = fmaf(y, wk_i, pre_i);
        float zf = fmaf(y, wk_f, pre_f);
        float zg = fmaf(y, wk_g, pre_g);
        float zo = fmaf(y, wk_o, pre_o);
        c = fsig(zf) * s0v + fsig(zi) * ftanh(zg);
        h = fsig(zo) * ftanh(c);

        // phase c: dpart[wv][m] = sum_{j<16} hc[16wv+j] * Wd[16wv+j][m]
        {
            float hv = hv_sel ? h : c;
            float p0 = 0.0f, p1 = 0.0f, p2 = 0.0f, p3 = 0.0f;
            #pragma unroll
            for (int j = 0; j < 4; j++) {
                p0 = fmaf(rdlane(hv, base16 + j),      wd_r[j],      p0);
                p1 = fmaf(rdlane(hv, base16 + 4 + j),  wd_r[4 + j],  p1);
                p2 = fmaf(rdlane(hv, base16 + 8 + j),  wd_r[8 + j],  p2);
                p3 = fmaf(rdlane(hv, base16 + 12 + j), wd_r[12 + j], p3);
            }
            dpart[wv * DPST + lane] = (p0 + p1) + (p2 + p3);
        }
        __syncthreads();  // B1

        // phase d: wave wv reduces dproj slice m in [8wv, 8wv+8), pre-scaled K2
        {
            int w  = lane & 7;
            int mi = lane >> 3;
            float v = dpart[w * DPST + 8 * wv + mi];
            v += dppmov<0x111>(v);
            v += dppmov<0x112>(v);
            v += dppmov<0x114>(v);
            if ((lane & 7) == 7) dproj_s[8 * wv + mi] = K2C * (v + bwd_r);
        }
        __syncthreads();  // B2

        // phase e: e[t] = sum_m vd*tanh(dproj+Ue); store exp(e) (|e|<~3, safe)
        {
            const float4* dp4 = (const float4*)(dproj_s + m0);
            float4 d0 = dp4[0], d1 = dp4[1], d2 = dp4[2], d3 = dp4[3];
            float a0 = sumvd16, a1 = 0.0f, a2 = 0.0f, a3 = 0.0f;
            a0 = fmaf(vdr2[0],  frcp(1.0f + fexp2(d0.x + ue_r[0])),  a0);
            a1 = fmaf(vdr2[1],  frcp(1.0f + fexp2(d0.y + ue_r[1])),  a1);
            a2 = fmaf(vdr2[2],  frcp(1.0f + fexp2(d0.z + ue_r[2])),  a2);
            a3 = fmaf(vdr2[3],  frcp(1.0f + fexp2(d0.w + ue_r[3])),  a3);
            a0 = fmaf(vdr2[4],  frcp(1.0f + fexp2(d1.x + ue_r[4])),  a0);
            a1 = fmaf(vdr2[5],  frcp(1.0f + fexp2(d1.y + ue_r[5])),  a1);
            a2 = fmaf(vdr2[6],  frcp(1.0f + fexp2(d1.z + ue_r[6])),  a2);
            a3 = fmaf(vdr2[7],  frcp(1.0f + fexp2(d1.w + ue_r[7])),  a3);
            a0 = fmaf(vdr2[8],  frcp(1.0f + fexp2(d2.x + ue_r[8])),  a0);
            a1 = fmaf(vdr2[9],  frcp(1.0f + fexp2(d2.y + ue_r[9])),  a1);
            a2 = fmaf(vdr2[10], frcp(1.0f + fexp2(d2.z + ue_r[10])), a2);
            a3 = fmaf(vdr2[11], frcp(1.0f + fexp2(d2.w + ue_r[11])), a3);
            a0 = fmaf(vdr2[12], frcp(1.0f + fexp2(d3.x + ue_r[12])), a0);
            a1 = fmaf(vdr2[13], frcp(1.0f + fexp2(d3.y + ue_r[13])), a1);
            a2 = fmaf(vdr2[14], frcp(1.0f + fexp2(d3.z + ue_r[14])), a2);
            a3 = fmaf(vdr2[15], frcp(1.0f + fexp2(d3.w + ue_r[15])), a3);
            float acc = (a0 + a1) + (a2 + a3);
            acc += dppmov<0x111>(acc);
            acc += dppmov<0x112>(acc);
            if (q_e == 3) e_s[t_e] = fexp(acc + bvd0);
        }
        __syncthreads();  // B3

        // phase f: softmax denom (DPP) + ctx partials from registers + ys
        {
            float ex0 = e_s[lane];
            float ex1 = e_s[64 + lane];
            float invS = frcp(wavesum(ex0 + ex1));
            float exv = hv_sel ? ex0 : ex1;   // wave's 16 t's live in one half
            float p0 = 0.0f, p1 = 0.0f, p2 = 0.0f, p3 = 0.0f;
            #pragma unroll
            for (int j = 0; j < 4; j++) {
                p0 = fmaf(rdlane(exv, base16 + j),      enc_r[j],      p0);
                p1 = fmaf(rdlane(exv, base16 + 4 + j),  enc_r[4 + j],  p1);
                p2 = fmaf(rdlane(exv, base16 + 8 + j),  enc_r[8 + j],  p2);
                p3 = fmaf(rdlane(exv, base16 + 12 + j), enc_r[12 + j], p3);
            }
            float ctxv = ((p0 + p1) + (p2 + p3)) * invS;
            ctxp[wv * 64 + lane] = ctxv;
            float yw = ctxv * Wde;
            yw += dppmov<0x111>(yw);
            yw += dppmov<0x112>(yw);
            yw += dppmov<0x114>(yw);
            yw += dppmov<0x118>(yw);
            yw += dppmov<0x142>(yw);
            yw += dppmov<0x143>(yw);
            if (lane == 63) ys_s[wv] = yw;
        }
        __syncthreads();  // B4
    }

    // ---- epilogue: out[b][p] = ((concat(h,ctx) @ Wvb + bvb) * Wb[p]) + bWb[p] ----
    if (wv == 0) {
        float ctxm = 0.0f;
        #pragma unroll
        for (int w = 0; w < NW; w++) ctxm += ctxp[w * 64 + lane];
        float part = h * Wvb[lane] + ctxm * Wvb[64 + lane];
        float v = wavesum(part) + bvb[0];
        out[(size_t)b * Pn + lane] = fmaf(v, Wb[lane], bWb[lane]);
    }
}

extern "C" void kernel_launch(void* const* d_in, const int* in_sizes, int n_in,
                              void* d_out, int out_size, void* d_ws, size_t ws_size,
                              hipStream_t stream) {
    const float* data    = (const float*)d_in[0];
    const float* enc     = (const float*)d_in[1];
    const float* h0      = (const float*)d_in[2];
    const float* s0      = (const float*)d_in[3];
    const float* W_dense = (const float*)d_in[4];
    const float* b_dense = (const float*)d_in[5];
    const float* Wk      = (const float*)d_in[6];
    const float* Uk      = (const float*)d_in[7];
    const float* bk      = (const float*)d_in[8];
    const float* Wd      = (const float*)d_in[9];
    const float* bWd     = (const float*)d_in[10];
    const float* Ud      = (const float*)d_in[11];
    const float* bUd     = (const float*)d_in[12];
    const float* vd      = (const float*)d_in[13];
    const float* bvd     = (const float*)d_in[14];
    const float* Wvb     = (const float*)d_in[15];
    const float* bvb     = (const float*)d_in[16];
    const float* Wb      = (const float*)d_in[17];
    const float* bWb     = (const float*)d_in[18];

    decoder_kernel<<<Bn, NTH, SMEM_FLOATS * sizeof(float), stream>>>(
        data, enc, h0, s0, W_dense, b_dense, Wk, Uk, bk,
        Wd, bWd, Ud, bUd, vd, bvd, Wvb, bvb, Wb, bWb, (float*)d_out);
}